// Round 8
// baseline (44.611 us; speedup 1.0000x reference)
//
#include <hip/hip_runtime.h>
#include <cfloat>

// DistLoss: out = sum_m min_{s,n} ||surfaces[s,n,:] - targets[m,:]||^2
// surfaces: [4,4096,3] f32 (flat SN=16384), targets: [16384,3] f32.
//
// R8: MFMA (16x16x32 bf16, split-bf16 K=11 slots) as R7, restructured:
//   - 16 B-fragments per wave (256 targets) -> 16 back-to-back independent
//     MFMAs per A-tile (310 SIMD-cyc of matrix work per 1 A-load).
//   - 2-deep A-tile prefetch: load for tile r+2 issued before computing
//     tile r -> ~620 cyc of compute covers L2 latency at 2 waves/SIMD.
//   dist(p,m) = sum_k A[p,k]*B[k,m]; per coord (hi,hi,lo)x(hi,lo,hi),
//   s2 as (s2_hi,s2_lo)x(1,1); b2[m] added after the min.
//  k0: build Aex[SN][32], Bex[M][32] (bf16), b2f[M]; reset counter.
//  k1: 512 blocks x 4 waves; wave wg: target group g=wg&63 (256 targets),
//      point chunk c=wg>>6 (512 points = 32 A-tiles).
//  k2: 256 blocks: min over 32 chunks + b2, block-sum -> part[256];
//      last block (election) sums part -> out. Fixed order -> deterministic.

namespace {
constexpr int M   = 16384;
constexpr int SN  = 16384;
constexpr int NCH = 32;           // point chunks
constexpr int PPC = SN / NCH;     // 512 points per chunk
constexpr int NG  = 64;           // target groups
constexpr int TPG = 256;          // targets per group (16 frags x 16)
constexpr int FR  = 16;           // B fragments per wave
constexpr int K2B = 256;
}

typedef short bf16x8 __attribute__((ext_vector_type(8)));
typedef float f32x4  __attribute__((ext_vector_type(4)));

static __device__ __forceinline__ unsigned short f2bf(float f) {
  unsigned int u = __builtin_bit_cast(unsigned int, f);
  return (unsigned short)((u + 0x7FFFu + ((u >> 16) & 1u)) >> 16);
}
static __device__ __forceinline__ float bf2f(unsigned short h) {
  unsigned int u = ((unsigned int)h) << 16;
  return __builtin_bit_cast(float, u);
}
static __device__ __forceinline__ float min3f(float a, float b, float c) {
  return fminf(fminf(a, b), c);   // v_min3_f32
}

__global__ __launch_bounds__(256) void build_ab(
    const float* __restrict__ surf, const float* __restrict__ tgt,
    unsigned short* __restrict__ Aex, unsigned short* __restrict__ Bex,
    float* __restrict__ b2f, unsigned* __restrict__ counter)
{
  const int i = blockIdx.x * 256 + threadIdx.x;
  if (i == 0) counter[0] = 0u;

  {  // A row: point i
    const float x = surf[(size_t)i*3+0], y = surf[(size_t)i*3+1], z = surf[(size_t)i*3+2];
    const float s2 = fmaf(x, x, fmaf(y, y, z * z));
    unsigned short row[32];
#pragma unroll
    for (int k = 0; k < 32; ++k) row[k] = 0;
    const float cs[3] = {x, y, z};
#pragma unroll
    for (int c = 0; c < 3; ++c) {
      const unsigned short hi = f2bf(cs[c]);
      const unsigned short lo = f2bf(cs[c] - bf2f(hi));
      row[3*c+0] = hi; row[3*c+1] = hi; row[3*c+2] = lo;
    }
    const unsigned short shi = f2bf(s2);
    const unsigned short slo = f2bf(s2 - bf2f(shi));
    row[9] = shi; row[10] = slo;
#pragma unroll
    for (int k = 0; k < 16; ++k)
      ((unsigned int*)(Aex + (size_t)i*32))[k] =
          (unsigned int)row[2*k] | ((unsigned int)row[2*k+1] << 16);
  }
  {  // B row: target i
    const float a = tgt[(size_t)i*3+0], b = tgt[(size_t)i*3+1], c = tgt[(size_t)i*3+2];
    b2f[i] = fmaf(a, a, fmaf(b, b, c * c));
    const float us[3] = {-2.0f*a, -2.0f*b, -2.0f*c};
    unsigned short row[32];
#pragma unroll
    for (int k = 0; k < 32; ++k) row[k] = 0;
#pragma unroll
    for (int q = 0; q < 3; ++q) {
      const unsigned short hi = f2bf(us[q]);
      const unsigned short lo = f2bf(us[q] - bf2f(hi));
      row[3*q+0] = hi; row[3*q+1] = lo; row[3*q+2] = hi;
    }
    const unsigned short one = f2bf(1.0f);
    row[9] = one; row[10] = one;
#pragma unroll
    for (int k = 0; k < 16; ++k)
      ((unsigned int*)(Bex + (size_t)i*32))[k] =
          (unsigned int)row[2*k] | ((unsigned int)row[2*k+1] << 16);
  }
}

__global__ __launch_bounds__(256, 2) void dist_mfma(
    const unsigned short* __restrict__ Aex,
    const unsigned short* __restrict__ Bex,
    float* __restrict__ wmin)          // [NCH][M]
{
  const int tid  = threadIdx.x;
  const int lane = tid & 63;
  const int wid  = tid >> 6;
  const int wg   = blockIdx.x * 4 + wid;     // 0..2047
  const int g    = wg & (NG - 1);            // target group 0..63
  const int c    = wg >> 6;                  // point chunk 0..31
  const int m0   = g * TPG;
  const int r15  = lane & 15;
  const int koff = (lane >> 4) * 8;          // k-slice of 8 bf16

  // 16 B fragments: targets m0 + f*16 + r15, k-slice koff
  bf16x8 bfr[FR];
#pragma unroll
  for (int f = 0; f < FR; ++f)
    bfr[f] = *(const bf16x8*)(Bex + ((size_t)(m0 + f*16 + r15)) * 32 + koff);

  float mn[FR];
#pragma unroll
  for (int f = 0; f < FR; ++f) mn[f] = FLT_MAX;

  const unsigned short* ap = Aex + ((size_t)(c * PPC + r15)) * 32 + koff;
  // one A-tile = 16 rows x 64B = 1024B stride

#define LD_A(r)  (*(const bf16x8*)(ap + (size_t)(r) * 16 * 32))
#define COMPUTE(AT)                                                        \
  {                                                                        \
    _Pragma("unroll")                                                      \
    for (int f = 0; f < FR; ++f) {                                         \
      const f32x4 d = __builtin_amdgcn_mfma_f32_16x16x32_bf16(             \
          AT, bfr[f], (f32x4){0.f, 0.f, 0.f, 0.f}, 0, 0, 0);               \
      mn[f] = min3f(mn[f], fminf(d[0], d[1]), fminf(d[2], d[3]));          \
    }                                                                      \
  }

  bf16x8 a0 = LD_A(0);
  bf16x8 a1 = LD_A(1);
  for (int r = 0; r < PPC / 16; r += 2) {
    const int r2 = (r + 2 < PPC / 16) ? r + 2 : PPC / 16 - 1;  // clamp: dummy
    const int r3 = (r + 3 < PPC / 16) ? r + 3 : PPC / 16 - 1;
    bf16x8 a2 = LD_A(r2);
    COMPUTE(a0);
    bf16x8 a3 = LD_A(r3);
    COMPUTE(a1);
    a0 = a2; a1 = a3;
  }
#undef COMPUTE
#undef LD_A

  // combine the 4 row-groups (lane ^ 16, lane ^ 32)
#pragma unroll
  for (int f = 0; f < FR; ++f) {
    float v = mn[f];
    v = fminf(v, __shfl_xor(v, 16, 64));
    v = fminf(v, __shfl_xor(v, 32, 64));
    mn[f] = v;
  }
  if (lane < 16) {
#pragma unroll
    for (int f = 0; f < FR; ++f)
      wmin[(size_t)c * M + m0 + f * 16 + lane] = mn[f];
  }
}

__global__ __launch_bounds__(256) void dist_min_sum(
    const float* __restrict__ wmin,   // [NCH][M]
    const float* __restrict__ b2f,    // [M]
    float* __restrict__ part,         // [K2B]
    unsigned* __restrict__ counter,
    float* __restrict__ out)
{
  const int tid  = threadIdx.x;
  const int lane = tid & 63;
  const int w    = tid >> 6;                 // wave 0..3 -> 8 chunks each
  const int m    = blockIdx.x * 64 + lane;

  float mnv = FLT_MAX;
  const int c0 = w * (NCH / 4);
#pragma unroll
  for (int ci = 0; ci < NCH / 4; ++ci)
    mnv = fminf(mnv, wmin[(size_t)(c0 + ci) * M + m]);

  __shared__ float red[4][64];
  red[w][lane] = mnv;
  __syncthreads();

  if (w == 0) {
    float v = fminf(fminf(red[0][lane], red[1][lane]),
                    fminf(red[2][lane], red[3][lane]));
    v += b2f[m];
    for (int off = 32; off; off >>= 1) v += __shfl_down(v, off, 64);

    unsigned done = 0;
    if (lane == 0) {
      part[blockIdx.x] = v;
      __threadfence();
      done = atomicAdd(counter, 1u);
    }
    done = __shfl(done, 0, 64);

    if (done == (unsigned)(K2B - 1)) {        // last block finalizes
      __threadfence();
      float s = 0.0f;
#pragma unroll
      for (int i = 0; i < K2B / 64; ++i) s += part[i * 64 + lane];
      for (int off = 32; off; off >>= 1) s += __shfl_down(s, off, 64);
      if (lane == 0) out[0] = s;
    }
  }
}

extern "C" void kernel_launch(void* const* d_in, const int* in_sizes, int n_in,
                              void* d_out, int out_size, void* d_ws, size_t ws_size,
                              hipStream_t stream) {
  const float* surf = (const float*)d_in[0];   // 4*4096*3
  const float* tgt  = (const float*)d_in[1];   // 16384*3
  float* out = (float*)d_out;

  unsigned short* Aex = (unsigned short*)d_ws;             // SN*32*2  = 1 MB
  unsigned short* Bex = Aex + (size_t)SN * 32;             // M*32*2   = 1 MB
  float* b2f  = (float*)(Bex + (size_t)M * 32);            // M*4      = 64 KB
  float* wmin = b2f + M;                                   // NCH*M*4  = 2 MB
  float* part = wmin + (size_t)NCH * M;                    // K2B*4
  unsigned* counter = (unsigned*)(part + K2B);             // 4 B

  build_ab<<<SN / 256, 256, 0, stream>>>(surf, tgt, Aex, Bex, b2f, counter);
  dist_mfma<<<(NG * NCH) / 4, 256, 0, stream>>>(Aex, Bex, wmin);
  dist_min_sum<<<K2B, 256, 0, stream>>>(wmin, b2f, part, counter, out);
}

// Round 9
// 40.493 us; speedup vs baseline: 1.1017x; 1.1017x over previous
//
#include <hip/hip_runtime.h>
#include <cfloat>

// DistLoss: out = sum_m min_{s,n} ||surfaces[s,n,:] - targets[m,:]||^2
// surfaces: [4,4096,3] f32 (flat SN=16384), targets: [16384,3] f32.
//
// R9 = R7 verbatim (R8's FR=16 spilled to scratch: VGPR_Count=56 < 64 regs
// of B-frags -> scratch reloads; revert to FR=8, no spill).
//
// MFMA (16x16x32 bf16) with split-bf16 precision.
//   dist(p,m) = sum_k A[p,k]*B[k,m], K-slots (11 used, 21 zero):
//     per coord c: A=(hi,hi,lo) x B=(hi,lo,hi)  -> hi*hi + hi*lo + lo*hi
//     s2:          A=(s2_hi,s2_lo) x B=(1,1)
//   b2[m] added after the min (constant per target).
//  k0: build A_exp[SN][32], B_exp[M][32] (bf16), b2f[M]; reset counter.
//  k1: 1024 blocks x 4 waves. Each wave: 8 B-frags in regs (128 targets),
//      streams 512 points (32 A-tiles, reg-prefetched from L2), 8 mfma +
//      min3 per tile; cross-lane min (xor 16,32); writes wmin[c][128 tgts].
//  k2: 256 blocks: min over 32 chunks + b2, wave-sum -> part[256];
//      last block (election) sums part -> out. Fixed order -> deterministic.

namespace {
constexpr int M   = 16384;
constexpr int SN  = 16384;
constexpr int NCH = 32;           // point chunks
constexpr int PPC = SN / NCH;     // 512 points per chunk
constexpr int NG  = 128;          // target groups
constexpr int TPG = 128;          // targets per group (8 frags x 16)
constexpr int K2B = 256;
}

typedef short bf16x8 __attribute__((ext_vector_type(8)));
typedef float f32x4  __attribute__((ext_vector_type(4)));

static __device__ __forceinline__ unsigned short f2bf(float f) {
  unsigned int u = __builtin_bit_cast(unsigned int, f);
  return (unsigned short)((u + 0x7FFFu + ((u >> 16) & 1u)) >> 16);
}
static __device__ __forceinline__ float bf2f(unsigned short h) {
  unsigned int u = ((unsigned int)h) << 16;
  return __builtin_bit_cast(float, u);
}

__global__ __launch_bounds__(256) void build_ab(
    const float* __restrict__ surf, const float* __restrict__ tgt,
    unsigned short* __restrict__ Aex, unsigned short* __restrict__ Bex,
    float* __restrict__ b2f, unsigned* __restrict__ counter)
{
  const int i = blockIdx.x * 256 + threadIdx.x;
  if (i == 0) counter[0] = 0u;

  {  // A row: point i
    const float x = surf[(size_t)i*3+0], y = surf[(size_t)i*3+1], z = surf[(size_t)i*3+2];
    const float s2 = fmaf(x, x, fmaf(y, y, z * z));
    unsigned short row[32];
#pragma unroll
    for (int k = 0; k < 32; ++k) row[k] = 0;
    const float cs[3] = {x, y, z};
#pragma unroll
    for (int c = 0; c < 3; ++c) {
      const unsigned short hi = f2bf(cs[c]);
      const unsigned short lo = f2bf(cs[c] - bf2f(hi));
      row[3*c+0] = hi; row[3*c+1] = hi; row[3*c+2] = lo;
    }
    const unsigned short shi = f2bf(s2);
    const unsigned short slo = f2bf(s2 - bf2f(shi));
    row[9] = shi; row[10] = slo;
#pragma unroll
    for (int k = 0; k < 16; ++k)
      ((unsigned int*)(Aex + (size_t)i*32))[k] =
          (unsigned int)row[2*k] | ((unsigned int)row[2*k+1] << 16);
  }
  {  // B row: target i
    const float a = tgt[(size_t)i*3+0], b = tgt[(size_t)i*3+1], c = tgt[(size_t)i*3+2];
    b2f[i] = fmaf(a, a, fmaf(b, b, c * c));
    const float us[3] = {-2.0f*a, -2.0f*b, -2.0f*c};
    unsigned short row[32];
#pragma unroll
    for (int k = 0; k < 32; ++k) row[k] = 0;
#pragma unroll
    for (int q = 0; q < 3; ++q) {
      const unsigned short hi = f2bf(us[q]);
      const unsigned short lo = f2bf(us[q] - bf2f(hi));
      row[3*q+0] = hi; row[3*q+1] = lo; row[3*q+2] = hi;
    }
    const unsigned short one = f2bf(1.0f);
    row[9] = one; row[10] = one;
#pragma unroll
    for (int k = 0; k < 16; ++k)
      ((unsigned int*)(Bex + (size_t)i*32))[k] =
          (unsigned int)row[2*k] | ((unsigned int)row[2*k+1] << 16);
  }
}

__global__ __launch_bounds__(256, 4) void dist_mfma(
    const unsigned short* __restrict__ Aex,
    const unsigned short* __restrict__ Bex,
    float* __restrict__ wmin)          // [NCH][M]
{
  const int tid  = threadIdx.x;
  const int lane = tid & 63;
  const int wid  = tid >> 6;
  const int wg   = blockIdx.x * 4 + wid;     // 0..4095
  const int g    = wg & (NG - 1);            // target group 0..127
  const int c    = wg >> 7;                  // point chunk 0..31
  const int m0   = g * TPG;
  const int r15  = lane & 15;
  const int koff = (lane >> 4) * 8;          // k-slice of 8 bf16

  // 8 B fragments: targets m0 + f*16 + r15, k-slice koff
  bf16x8 bfr[8];
#pragma unroll
  for (int f = 0; f < 8; ++f)
    bfr[f] = *(const bf16x8*)(Bex + ((size_t)(m0 + f*16 + r15)) * 32 + koff);

  float mn[8];
#pragma unroll
  for (int f = 0; f < 8; ++f) mn[f] = FLT_MAX;

  const int pbase = c * PPC;
  const unsigned short* ap = Aex + ((size_t)(pbase + r15)) * 32 + koff;

  bf16x8 acur = *(const bf16x8*)ap;
  for (int r = 0; r < PPC / 16; ++r) {
    const int rn = (r + 1 < PPC / 16) ? r + 1 : r;     // last iter: dummy reload
    const bf16x8 anxt = *(const bf16x8*)(ap + (size_t)rn * 16 * 32);
#pragma unroll
    for (int f = 0; f < 8; ++f) {
      const f32x4 d = __builtin_amdgcn_mfma_f32_16x16x32_bf16(
          acur, bfr[f], (f32x4){0.f, 0.f, 0.f, 0.f}, 0, 0, 0);
      mn[f] = fminf(fminf(mn[f], fminf(d[0], d[1])), fminf(d[2], d[3]));
    }
    acur = anxt;
  }

  // combine the 4 row-groups (lane ^ 16, lane ^ 32)
#pragma unroll
  for (int f = 0; f < 8; ++f) {
    float v = mn[f];
    v = fminf(v, __shfl_xor(v, 16, 64));
    v = fminf(v, __shfl_xor(v, 32, 64));
    mn[f] = v;
  }
  if (lane < 16) {
#pragma unroll
    for (int f = 0; f < 8; ++f)
      wmin[(size_t)c * M + m0 + f * 16 + lane] = mn[f];
  }
}

__global__ __launch_bounds__(256) void dist_min_sum(
    const float* __restrict__ wmin,   // [NCH][M]
    const float* __restrict__ b2f,    // [M]
    float* __restrict__ part,         // [K2B]
    unsigned* __restrict__ counter,
    float* __restrict__ out)
{
  const int tid  = threadIdx.x;
  const int lane = tid & 63;
  const int w    = tid >> 6;                 // wave 0..3 -> 8 chunks each
  const int m    = blockIdx.x * 64 + lane;

  float mnv = FLT_MAX;
  const int c0 = w * (NCH / 4);
#pragma unroll
  for (int ci = 0; ci < NCH / 4; ++ci)
    mnv = fminf(mnv, wmin[(size_t)(c0 + ci) * M + m]);

  __shared__ float red[4][64];
  red[w][lane] = mnv;
  __syncthreads();

  if (w == 0) {
    float v = fminf(fminf(red[0][lane], red[1][lane]),
                    fminf(red[2][lane], red[3][lane]));
    v += b2f[m];
    for (int off = 32; off; off >>= 1) v += __shfl_down(v, off, 64);

    unsigned done = 0;
    if (lane == 0) {
      part[blockIdx.x] = v;
      __threadfence();
      done = atomicAdd(counter, 1u);
    }
    done = __shfl(done, 0, 64);

    if (done == (unsigned)(K2B - 1)) {        // last block finalizes
      __threadfence();
      float s = 0.0f;
#pragma unroll
      for (int i = 0; i < K2B / 64; ++i) s += part[i * 64 + lane];
      for (int off = 32; off; off >>= 1) s += __shfl_down(s, off, 64);
      if (lane == 0) out[0] = s;
    }
  }
}

extern "C" void kernel_launch(void* const* d_in, const int* in_sizes, int n_in,
                              void* d_out, int out_size, void* d_ws, size_t ws_size,
                              hipStream_t stream) {
  const float* surf = (const float*)d_in[0];   // 4*4096*3
  const float* tgt  = (const float*)d_in[1];   // 16384*3
  float* out = (float*)d_out;

  unsigned short* Aex = (unsigned short*)d_ws;             // SN*32*2  = 1 MB
  unsigned short* Bex = Aex + (size_t)SN * 32;             // M*32*2   = 1 MB
  float* b2f  = (float*)(Bex + (size_t)M * 32);            // M*4      = 64 KB
  float* wmin = b2f + M;                                   // NCH*M*4  = 2 MB
  float* part = wmin + (size_t)NCH * M;                    // K2B*4
  unsigned* counter = (unsigned*)(part + K2B);             // 4 B

  build_ab<<<SN / 256, 256, 0, stream>>>(surf, tgt, Aex, Bex, b2f, counter);
  dist_mfma<<<(NG * NCH) / 4, 256, 0, stream>>>(Aex, Bex, wmin);
  dist_min_sum<<<K2B, 256, 0, stream>>>(wmin, b2f, part, counter, out);
}